// Round 10
// baseline (288.535 us; speedup 1.0000x reference)
//
#include <hip/hip_runtime.h>
#include <math.h>

#define B_SZ 32
#define L_SZ 32768
#define T_SZ 1024
#define PS_SZ 32
#define D_SZ 256
#define SM_M 10.0f   // static softmax max-shift; scores ~N(0,1), max << 10

typedef float f32x4 __attribute__((ext_vector_type(4)));
typedef short s16x8 __attribute__((ext_vector_type(8)));
typedef unsigned short u16x8 __attribute__((ext_vector_type(8)));

__device__ __forceinline__ unsigned short f2bf(float f) {
  union { float f; unsigned int u; } v; v.f = f;
  unsigned int r = v.u + 0x7FFFu + ((v.u >> 16) & 1u);
  return (unsigned short)(r >> 16);
}

__device__ __forceinline__ void g2l16(const unsigned short* g, unsigned short* l) {
  __builtin_amdgcn_global_load_lds(
      (const __attribute__((address_space(1))) unsigned int*)g,
      (__attribute__((address_space(3))) unsigned int*)l, 16, 0, 0);
}

// ---------------- prep subroutines ----------------
__device__ __forceinline__ void phaseA_stats(const float* x, float* sgpart, int g, int tid,
                                             int w, int lane, float* red) {
  const int b = g >> 3;
  const float* p = x + (size_t)b * L_SZ + (size_t)(g & 7) * 4096;
  float s = 0.f, ss = 0.f;
#pragma unroll
  for (int i = 0; i < 4; ++i) {
    float4 f = ((const float4*)p)[tid + i * 256];
    s += f.x + f.y + f.z + f.w;
    ss += f.x * f.x + f.y * f.y + f.z * f.z + f.w * f.w;
  }
#pragma unroll
  for (int off = 32; off >= 1; off >>= 1) {
    s += __shfl_down(s, off);
    ss += __shfl_down(ss, off);
  }
  if (lane == 0) { red[w] = s; red[4 + w] = ss; }
  __syncthreads();
  if (tid == 0) {
    sgpart[g * 2]     = red[0] + red[1] + red[2] + red[3];
    sgpart[g * 2 + 1] = red[4] + red[5] + red[6] + red[7];
  }
}

__device__ __forceinline__ void phaseA_folds(int idx, const float* Wp, const float* bp,
                                             const float* Wq, const float* bq,
                                             const float* Wo, const float* bo,
                                             const float* Wh, const float* bh,
                                             float* Wcb, unsigned short* WqT,
                                             unsigned short* WfT, float* bfp) {
  if (idx < 33 * 768) {
    int p = idx / 768, j = idx % 768;
    const float* arow = (p < 32) ? (Wp + p * 256) : bp;
    float acc = (p < 32) ? 0.f : bq[j];
    for (int d = 0; d < 256; ++d) acc += arow[d] * Wq[d * 768 + j];
    if (p < 32) WqT[j * 32 + p] = f2bf(acc);
    else Wcb[j] = acc;
  } else {
    int k = idx - 33 * 768;
    if (k < 8192) {
      int p = k >> 8, d = k & 255;
      float acc = 0.f;
      for (int e = 0; e < 256; ++e) acc += Wo[d * 256 + e] * Wh[e * 32 + p];
      WfT[p * 256 + d] = f2bf(acc);
    } else if (k < 8224) {
      int p = k - 8192;
      float acc = bh[p];
      for (int e = 0; e < 256; ++e) acc += bo[e] * Wh[e * 32 + p];
      bfp[p] = acc;
    }
  }
}

// ---------------- prep kernel: stats + folds + zero counters ----------------
__global__ __launch_bounds__(256) void prep_kernel(const float* __restrict__ x,
                                                   float* __restrict__ sgpart,
                                                   const float* __restrict__ Wp,
                                                   const float* __restrict__ bp,
                                                   const float* __restrict__ Wq,
                                                   const float* __restrict__ bq,
                                                   const float* __restrict__ Wo,
                                                   const float* __restrict__ bo,
                                                   const float* __restrict__ Wh,
                                                   const float* __restrict__ bh,
                                                   float* __restrict__ Wcb,
                                                   unsigned short* __restrict__ WqT,
                                                   unsigned short* __restrict__ WfT,
                                                   float* __restrict__ bfp,
                                                   unsigned int* __restrict__ ctrs) {
  __shared__ float red[8];
  const int g = blockIdx.x, tid = threadIdx.x;
  const int w = tid >> 6, lane = tid & 63;
  if (g < 256) {
    phaseA_stats(x, sgpart, g, tid, w, lane, red);
  } else if (g < 388) {
    phaseA_folds((g - 256) * 256 + tid, Wp, bp, Wq, bq, Wo, bo, Wh, bh, Wcb, WqT, WfT, bfp);
  } else {
    if (tid < 33) ctrs[tid] = 0u;  // done_b[32] + total
  }
}

// ---------------- flash-attention tile (verified R7/R9 code) ----------------
__device__ __forceinline__ float attn_tile(const unsigned short* Qb,
                                           const unsigned short* Kb,
                                           const unsigned short* Vtt,
                                           const unsigned short* WfT, const float* bfp,
                                           const float* x, const float* sgpart,
                                           unsigned short* SMEM, int b, int qt,
                                           int tid, int w, int lane, int lo, int quad) {
  const int qr0 = qt * 64 + w * 16;
  const size_t kbase = (size_t)b << 10;

  s16x8 qf[8];
  const size_t qrow = (kbase + qr0 + lo) * 256;
#pragma unroll
  for (int kc = 0; kc < 8; ++kc) qf[kc] = *(const s16x8*)&Qb[qrow + kc * 32 + quad * 8];

  f32x4 O[16];
#pragma unroll
  for (int nt = 0; nt < 16; ++nt) O[nt] = (f32x4){0.f, 0.f, 0.f, 0.f};
  f32x4 Ol = {0.f, 0.f, 0.f, 0.f};
  s16x8 ones;
#pragma unroll
  for (int jj = 0; jj < 8; ++jj) ones[jj] = (short)0x3F80;

  const int c16p = tid & 31;
  const int keyr = tid >> 5;
  const int c16s = (c16p & 24) | ((c16p & 7) ^ keyr);
  const unsigned short* kgp = Kb + (kbase << 8) + keyr * 256 + c16s * 8;
  const int dql = tid >> 2;
  const int cpq = (tid & 3) ^ ((tid >> 3) & 3);
  const unsigned short* vgp = Vtt + (size_t)b * 262144 + dql * 32 + cpq * 8;

  unsigned short* myp = &SMEM[16384 + w * 640];
  const int lo7 = lo & 7;
  const int nk = 2 * (qt + 1);

  for (int kt = 0; kt < nk; ++kt) {
    const int k0 = kt * 32;
    __syncthreads();
#pragma unroll
    for (int it = 0; it < 4; ++it)
      g2l16(kgp + it * 2048, &SMEM[(it * 256 + w * 64) * 8]);
#pragma unroll
    for (int it = 0; it < 4; ++it)
      g2l16(vgp + it * 2048, &SMEM[8192 + (it * 256 + w * 64) * 8]);
    kgp += 8192; vgp += 8192;
    __syncthreads();

    if (k0 <= qr0 + 15) {
      f32x4 s0 = {0.f, 0.f, 0.f, 0.f}, s1 = {0.f, 0.f, 0.f, 0.f};
#pragma unroll
      for (int kc = 0; kc < 8; ++kc) {
        const int c16 = kc * 4 + quad;
        const int cs = (c16 & 24) | ((c16 & 7) ^ lo7);
        s16x8 kf0 = *(const s16x8*)&SMEM[(lo * 32 + cs) * 8];
        s16x8 kf1 = *(const s16x8*)&SMEM[((16 + lo) * 32 + cs) * 8];
        s0 = __builtin_amdgcn_mfma_f32_16x16x32_bf16(qf[kc], kf0, s0, 0, 0, 0);
        s1 = __builtin_amdgcn_mfma_f32_16x16x32_bf16(qf[kc], kf1, s1, 0, 0, 0);
      }
      if (k0 + 31 > qr0) {
#pragma unroll
        for (int ii = 0; ii < 4; ++ii) {
          const int row = qr0 + quad * 4 + ii;
          if (k0 + lo > row) s0[ii] = -1e30f;
          if (k0 + 16 + lo > row) s1[ii] = -1e30f;
        }
      }
#pragma unroll
      for (int ii = 0; ii < 4; ++ii) {
        myp[(quad * 4 + ii) * 40 + lo]      = f2bf(__expf(s0[ii] - SM_M));
        myp[(quad * 4 + ii) * 40 + 16 + lo] = f2bf(__expf(s1[ii] - SM_M));
      }
      s16x8 pf = *(const s16x8*)&myp[lo * 40 + quad * 8];
      Ol = __builtin_amdgcn_mfma_f32_16x16x32_bf16(pf, ones, Ol, 0, 0, 0);
#pragma unroll
      for (int nt = 0; nt < 16; ++nt) {
        const int d = nt * 16 + lo;
        const int cp = quad ^ ((d >> 1) & 3);
        s16x8 vf = *(const s16x8*)&SMEM[8192 + ((d << 2) + cp) * 8];
        O[nt] = __builtin_amdgcn_mfma_f32_16x16x32_bf16(pf, vf, O[nt], 0, 0, 0);
      }
    }
  }
  __syncthreads();

  float inv4[4];
#pragma unroll
  for (int ii = 0; ii < 4; ++ii) inv4[ii] = 1.f / Ol[ii];
  unsigned short* OLw = &SMEM[w * 4224];
#pragma unroll
  for (int nt = 0; nt < 16; ++nt)
#pragma unroll
    for (int ii = 0; ii < 4; ++ii)
      OLw[(quad * 4 + ii) * 264 + nt * 16 + lo] = f2bf(O[nt][ii] * inv4[ii]);

  s16x8 af[8];
#pragma unroll
  for (int kc = 0; kc < 8; ++kc)
    af[kc] = *(const s16x8*)&OLw[lo * 264 + kc * 32 + quad * 8];

  float S = 0.f, SS = 0.f;
#pragma unroll
  for (int i = 0; i < 8; ++i) {
    S += sgpart[(b * 8 + i) * 2];
    SS += sgpart[(b * 8 + i) * 2 + 1];
  }
  const float mean = S * (1.f / (float)L_SZ);
  const float var = (SS - S * mean) * (1.f / (float)(L_SZ - 1));
  const float invb = 1.f / (sqrtf(var) + 1e-5f);

  float lacc = 0.f;
#pragma unroll
  for (int nt = 0; nt < 2; ++nt) {
    f32x4 acc = {0.f, 0.f, 0.f, 0.f};
#pragma unroll
    for (int kc = 0; kc < 8; ++kc) {
      s16x8 bfr = *(const s16x8*)&WfT[(size_t)(nt * 16 + lo) * 256 + kc * 32 + quad * 8];
      acc = __builtin_amdgcn_mfma_f32_16x16x32_bf16(af[kc], bfr, acc, 0, 0, 0);
    }
    const float ba = bfp[nt * 16 + lo];
    const int p = nt * 16 + lo;
#pragma unroll
    for (int ii = 0; ii < 4; ++ii) {
      const int t = qr0 + quad * 4 + ii;
      if (t < 1023) {
        const float pr = acc[ii] + ba;
        const float tg = (x[(size_t)b * L_SZ + (t + 1) * 32 + p] - mean) * invb;
        const float d = pr - tg;
        lacc += d * d;
      }
    }
  }
#pragma unroll
  for (int off = 32; off >= 1; off >>= 1) lacc += __shfl_down(lacc, off);
  float* redf = (float*)&SMEM[17024];
  if (lane == 0) redf[w] = lacc;
  __syncthreads();
  return redf[0] + redf[1] + redf[2] + redf[3];
}

// ---------------- fused qkv + attention (512 blocks, all co-resident) ----------------
__global__ __launch_bounds__(256, 2) void fused_kernel(const float* __restrict__ x,
                                                       const float* __restrict__ sgpart,
                                                       const unsigned short* __restrict__ WqT,
                                                       const float* __restrict__ Wcb,
                                                       const unsigned short* __restrict__ WfT,
                                                       const float* __restrict__ bfp,
                                                       unsigned short* __restrict__ Qb,
                                                       unsigned short* __restrict__ Kb,
                                                       unsigned short* __restrict__ Vtt,
                                                       unsigned int* __restrict__ done_b,
                                                       unsigned int* __restrict__ total,
                                                       float* __restrict__ lossb,
                                                       float* __restrict__ out) {
  __shared__ unsigned short SMEM[18944];  // 37888 B
  const int g = blockIdx.x;
  const int tid = threadIdx.x;
  const int w = tid >> 6, lane = tid & 63;
  const int lo = lane & 15, quad = lane >> 4;

  // XCD-pinned batch: producers and consumers of a b share an XCD (g%8 fixed per b-group)
  const int bq = (g & 7) * 4 + ((g >> 3) & 3);
  const int chunk = g >> 5;                       // 16 chunks per b
  const int r0 = bq * 1024 + chunk * 64 + w * 16; // wave's 16 rows

  // ===== qkv chunk (4 waves x 16 rows) =====
  {
    float S = 0.f, SS = 0.f;
#pragma unroll
    for (int i = 0; i < 8; ++i) {
      S += sgpart[(bq * 8 + i) * 2];
      SS += sgpart[(bq * 8 + i) * 2 + 1];
    }
    const float mean = S * (1.f / (float)L_SZ);
    const float var = (SS - S * mean) * (1.f / (float)(L_SZ - 1));
    const float inv = 1.f / (sqrtf(var) + 1e-5f);
    unsigned short* Tw = &SMEM[w * 4224];

    s16x8 af0;  // A[m=lo][k=quad*8+j], 16 rows, normalized inline
    {
      float4 a = *(const float4*)&x[(size_t)(r0 + lo) * 32 + quad * 8];
      float4 c = *(const float4*)&x[(size_t)(r0 + lo) * 32 + quad * 8 + 4];
      af0[0] = (short)f2bf((a.x - mean) * inv); af0[1] = (short)f2bf((a.y - mean) * inv);
      af0[2] = (short)f2bf((a.z - mean) * inv); af0[3] = (short)f2bf((a.w - mean) * inv);
      af0[4] = (short)f2bf((c.x - mean) * inv); af0[5] = (short)f2bf((c.y - mean) * inv);
      af0[6] = (short)f2bf((c.z - mean) * inv); af0[7] = (short)f2bf((c.w - mean) * inv);
    }
    // Q (cols 0..255, pre-scaled 1/16)
#pragma unroll 4
    for (int nt = 0; nt < 16; ++nt) {
      s16x8 bf = *(const s16x8*)&WqT[(size_t)(nt * 16 + lo) * 32 + quad * 8];
      f32x4 c0 = {0.f, 0.f, 0.f, 0.f};
      c0 = __builtin_amdgcn_mfma_f32_16x16x32_bf16(af0, bf, c0, 0, 0, 0);
      const int col = nt * 16 + lo;
      const float bi = Wcb[col];
#pragma unroll
      for (int i = 0; i < 4; ++i)
        Tw[(quad * 4 + i) * 264 + col] = f2bf((c0[i] + bi) * 0.0625f);
    }
#pragma unroll
    for (int it = 0; it < 8; ++it) {
      const int c = it * 64 + lane;
      const int row = c >> 5, c16 = c & 31;
      *(u16x8*)&Qb[(size_t)(r0 + row) * 256 + c16 * 8] = *(const u16x8*)&Tw[row * 264 + c16 * 8];
    }
    // K (cols 256..511)
#pragma unroll 4
    for (int nt = 0; nt < 16; ++nt) {
      s16x8 bf = *(const s16x8*)&WqT[(size_t)(256 + nt * 16 + lo) * 32 + quad * 8];
      f32x4 c0 = {0.f, 0.f, 0.f, 0.f};
      c0 = __builtin_amdgcn_mfma_f32_16x16x32_bf16(af0, bf, c0, 0, 0, 0);
      const int col = nt * 16 + lo;
      const float bi = Wcb[256 + col];
#pragma unroll
      for (int i = 0; i < 4; ++i)
        Tw[(quad * 4 + i) * 264 + col] = f2bf(c0[i] + bi);
    }
#pragma unroll
    for (int it = 0; it < 8; ++it) {
      const int c = it * 64 + lane;
      const int row = c >> 5, c16 = c & 31;
      *(u16x8*)&Kb[(size_t)(r0 + row) * 256 + c16 * 8] = *(const u16x8*)&Tw[row * 264 + c16 * 8];
    }
    // V transposed, kt-tiled: Vtt[(b*32 + kt)*8192 + d*32 + t_local]
#pragma unroll 4
    for (int nt2 = 0; nt2 < 16; ++nt2) {
      s16x8 aw = *(const s16x8*)&WqT[(size_t)(512 + nt2 * 16 + lo) * 32 + quad * 8];
      f32x4 c0 = {0.f, 0.f, 0.f, 0.f};
      c0 = __builtin_amdgcn_mfma_f32_16x16x32_bf16(aw, af0, c0, 0, 0, 0);  // D[d][lo]
#pragma unroll
      for (int i = 0; i < 4; ++i) {
        const int d = nt2 * 16 + quad * 4 + i;
        Tw[d * 16 + lo] = f2bf(c0[i] + Wcb[512 + d]);
      }
    }
    {
      const int ktq = chunk * 2 + (w >> 1);
      const int tb = (w & 1) * 16;
      const size_t vb = ((size_t)bq * 32 + ktq) * 8192;
#pragma unroll
      for (int it = 0; it < 8; ++it) {
        const int c = it * 64 + lane;
        const int d = c >> 1, half = c & 1;
        *(u16x8*)&Vtt[vb + d * 32 + tb + half * 8] = *(const u16x8*)&Tw[d * 16 + half * 8];
      }
    }
  }
  // publish chunk (device-scope)
  __threadfence();
  __syncthreads();
  if (tid == 0) atomicAdd(&done_b[bq], 1u);

  // ===== attention tile of the SAME b (balanced qt pairing: (c, 15-c) per CU) =====
  const int qt = (g >> 8) ? (15 - ((g >> 5) & 7)) : ((g >> 5) & 7);
  if (tid == 0) {
    while (atomicAdd(&done_b[bq], 0u) < 16u) __builtin_amdgcn_s_sleep(8);
  }
  __syncthreads();
  __threadfence();  // acquire: no stale lines for Q/K/V reads

  float bl = attn_tile(Qb, Kb, Vtt, WfT, bfp, x, sgpart, SMEM, bq, qt, tid, w, lane, lo, quad);

  // ===== in-kernel loss finalize =====
  unsigned int* flag = (unsigned int*)&SMEM[17100];
  if (tid == 0) {
    lossb[g] = bl;
    __threadfence();
    unsigned int prev = atomicAdd(total, 1u);
    flag[0] = (prev == 511u) ? 1u : 0u;
  }
  __syncthreads();
  if (flag[0]) {
    __threadfence();
    float acc = 0.f;
    for (int i = tid; i < 512; i += 256) acc += atomicAdd(&lossb[i], 0.0f);
#pragma unroll
    for (int off = 32; off >= 1; off >>= 1) acc += __shfl_down(acc, off);
    float* redf = (float*)&SMEM[17200];
    if (lane == 0) redf[w] = acc;
    __syncthreads();
    if (tid == 0)
      out[0] = (redf[0] + redf[1] + redf[2] + redf[3]) *
               (1.f / (float)(B_SZ * (T_SZ - 1) * PS_SZ));
  }
}

extern "C" void kernel_launch(void* const* d_in, const int* in_sizes, int n_in,
                              void* d_out, int out_size, void* d_ws, size_t ws_size,
                              hipStream_t stream) {
  const float* x      = (const float*)d_in[0];
  const float* W_proj = (const float*)d_in[1];
  const float* b_proj = (const float*)d_in[2];
  const float* W_qkv  = (const float*)d_in[3];
  const float* b_qkv  = (const float*)d_in[4];
  const float* W_out  = (const float*)d_in[5];
  const float* b_out  = (const float*)d_in[6];
  const float* W_head = (const float*)d_in[7];
  const float* b_head = (const float*)d_in[8];
  float* out = (float*)d_out;
  char* ws = (char*)d_ws;

  unsigned short* Qb     = (unsigned short*)ws;
  unsigned short* Kb     = (unsigned short*)(ws + (16ull << 20));
  unsigned short* Vtt    = (unsigned short*)(ws + (32ull << 20));
  char* tail = ws + (48ull << 20);
  float*          Wcb    = (float*)tail;                        // 768 fp32 folded qkv bias
  unsigned short* WqT    = (unsigned short*)(tail + 4096);      // 768x32 bf16
  unsigned short* WfT    = (unsigned short*)(tail + 65536);     // 32x256 bf16
  float*          bfp    = (float*)(tail + 98304);              // 32 fp32
  float*          sgpart = (float*)(tail + 102400);             // 256x2 fp32
  unsigned int*   done_b = (unsigned int*)(tail + 106496);      // 32 ctrs
  unsigned int*   total  = (unsigned int*)(tail + 106496 + 128);// 1 ctr (ctrs[32])
  float*          lossb  = (float*)(tail + 106752);             // 512 fp32

  prep_kernel<<<389, 256, 0, stream>>>(x, sgpart, W_proj, b_proj, W_qkv, b_qkv,
                                       W_out, b_out, W_head, b_head,
                                       Wcb, WqT, WfT, bfp, done_b);
  fused_kernel<<<512, 256, 0, stream>>>(x, sgpart, WqT, Wcb, WfT, bfp,
                                        Qb, Kb, Vtt, done_b, total, lossb, out);
}

// Round 11
// 163.173 us; speedup vs baseline: 1.7683x; 1.7683x over previous
//
#include <hip/hip_runtime.h>
#include <math.h>

#define B_SZ 32
#define L_SZ 32768
#define T_SZ 1024
#define PS_SZ 32
#define D_SZ 256
#define SM_M 10.0f   // static softmax max-shift; scores ~N(0,1), max << 10

typedef float f32x4 __attribute__((ext_vector_type(4)));
typedef short s16x8 __attribute__((ext_vector_type(8)));
typedef unsigned short u16x8 __attribute__((ext_vector_type(8)));

__device__ __forceinline__ unsigned short f2bf(float f) {
  union { float f; unsigned int u; } v; v.f = f;
  unsigned int r = v.u + 0x7FFFu + ((v.u >> 16) & 1u);
  return (unsigned short)(r >> 16);
}

__device__ __forceinline__ void g2l16(const unsigned short* g, unsigned short* l) {
  __builtin_amdgcn_global_load_lds(
      (const __attribute__((address_space(1))) unsigned int*)g,
      (__attribute__((address_space(3))) unsigned int*)l, 16, 0, 0);
}

// ---------------- prep: stats partials + weight folds + counter zero ----------------
__global__ __launch_bounds__(256) void prep_kernel(const float* __restrict__ x,
                                                   float* __restrict__ sgpart,
                                                   const float* __restrict__ Wp,
                                                   const float* __restrict__ bp,
                                                   const float* __restrict__ Wq,
                                                   const float* __restrict__ bq,
                                                   const float* __restrict__ Wo,
                                                   const float* __restrict__ bo,
                                                   const float* __restrict__ Wh,
                                                   const float* __restrict__ bh,
                                                   float* __restrict__ Wcb,
                                                   unsigned short* __restrict__ WqT,
                                                   unsigned short* __restrict__ WfT,
                                                   float* __restrict__ bfp,
                                                   unsigned int* __restrict__ total,
                                                   float* __restrict__ lsum) {
  __shared__ float red[8];
  const int g = blockIdx.x, tid = threadIdx.x;
  const int w = tid >> 6, lane = tid & 63;
  if (g < 256) {
    const int b = g >> 3;
    const float* p = x + (size_t)b * L_SZ + (size_t)(g & 7) * 4096;
    float s = 0.f, ss = 0.f;
#pragma unroll
    for (int i = 0; i < 4; ++i) {
      float4 f = ((const float4*)p)[tid + i * 256];
      s += f.x + f.y + f.z + f.w;
      ss += f.x * f.x + f.y * f.y + f.z * f.z + f.w * f.w;
    }
#pragma unroll
    for (int off = 32; off >= 1; off >>= 1) {
      s += __shfl_down(s, off);
      ss += __shfl_down(ss, off);
    }
    if (lane == 0) { red[w] = s; red[4 + w] = ss; }
    __syncthreads();
    if (tid == 0) {
      sgpart[g * 2]     = red[0] + red[1] + red[2] + red[3];
      sgpart[g * 2 + 1] = red[4] + red[5] + red[6] + red[7];
    }
  } else if (g < 388) {
    int idx = (g - 256) * 256 + tid;
    if (idx < 33 * 768) {
      int p = idx / 768, j = idx % 768;
      const float* arow = (p < 32) ? (Wp + p * 256) : bp;
      float acc = (p < 32) ? 0.f : bq[j];
      for (int d = 0; d < 256; ++d) acc += arow[d] * Wq[d * 768 + j];
      if (p < 32) WqT[j * 32 + p] = f2bf(acc);
      else Wcb[j] = acc;
    } else {
      int k = idx - 33 * 768;
      if (k < 8192) {
        int p = k >> 8, d = k & 255;
        float acc = 0.f;
        for (int e = 0; e < 256; ++e) acc += Wo[d * 256 + e] * Wh[e * 32 + p];
        WfT[p * 256 + d] = f2bf(acc);
      } else if (k < 8224) {
        int p = k - 8192;
        float acc = bh[p];
        for (int e = 0; e < 256; ++e) acc += bo[e] * Wh[e * 32 + p];
        bfp[p] = acc;
      }
    }
  } else {
    if (tid == 0) { total[0] = 0u; lsum[0] = 0.f; }
  }
}

// ---------------- qkv MFMA GEMM (verified R7/R9); V kt-tiled transposed ----------------
__global__ __launch_bounds__(256) void qkv_kernel(const float* __restrict__ x,
                                                  const float* __restrict__ sgpart,
                                                  const unsigned short* __restrict__ WqT,
                                                  const float* __restrict__ Wcb,
                                                  unsigned short* __restrict__ Qb,
                                                  unsigned short* __restrict__ Kb,
                                                  unsigned short* __restrict__ Vtt) {
  __shared__ unsigned short T4[4][8448];
  const int tid = threadIdx.x;
  const int w = tid >> 6, lane = tid & 63;
  const int lo = lane & 15, quad = lane >> 4;
  unsigned short* Tw = T4[w];
  const int mbase = blockIdx.x * 128 + w * 32;
  const int b = mbase >> 10;
  float S = 0.f, SS = 0.f;
#pragma unroll
  for (int i = 0; i < 8; ++i) {
    S += sgpart[(b * 8 + i) * 2];
    SS += sgpart[(b * 8 + i) * 2 + 1];
  }
  const float mean = S * (1.f / (float)L_SZ);
  const float var = (SS - S * mean) * (1.f / (float)(L_SZ - 1));
  const float inv = 1.f / (sqrtf(var) + 1e-5f);
  s16x8 af0, af1;
  {
    float4 a = *(const float4*)&x[(size_t)(mbase + lo) * 32 + quad * 8];
    float4 c = *(const float4*)&x[(size_t)(mbase + lo) * 32 + quad * 8 + 4];
    af0[0] = (short)f2bf((a.x - mean) * inv); af0[1] = (short)f2bf((a.y - mean) * inv);
    af0[2] = (short)f2bf((a.z - mean) * inv); af0[3] = (short)f2bf((a.w - mean) * inv);
    af0[4] = (short)f2bf((c.x - mean) * inv); af0[5] = (short)f2bf((c.y - mean) * inv);
    af0[6] = (short)f2bf((c.z - mean) * inv); af0[7] = (short)f2bf((c.w - mean) * inv);
    float4 d = *(const float4*)&x[(size_t)(mbase + 16 + lo) * 32 + quad * 8];
    float4 e = *(const float4*)&x[(size_t)(mbase + 16 + lo) * 32 + quad * 8 + 4];
    af1[0] = (short)f2bf((d.x - mean) * inv); af1[1] = (short)f2bf((d.y - mean) * inv);
    af1[2] = (short)f2bf((d.z - mean) * inv); af1[3] = (short)f2bf((d.w - mean) * inv);
    af1[4] = (short)f2bf((e.x - mean) * inv); af1[5] = (short)f2bf((e.y - mean) * inv);
    af1[6] = (short)f2bf((e.z - mean) * inv); af1[7] = (short)f2bf((e.w - mean) * inv);
  }
  // Q (pre-scaled 1/16)
#pragma unroll 4
  for (int nt = 0; nt < 16; ++nt) {
    s16x8 bf = *(const s16x8*)&WqT[(size_t)(nt * 16 + lo) * 32 + quad * 8];
    f32x4 c0 = {0.f, 0.f, 0.f, 0.f}, c1 = {0.f, 0.f, 0.f, 0.f};
    c0 = __builtin_amdgcn_mfma_f32_16x16x32_bf16(af0, bf, c0, 0, 0, 0);
    c1 = __builtin_amdgcn_mfma_f32_16x16x32_bf16(af1, bf, c1, 0, 0, 0);
    const int col = nt * 16 + lo;
    const float bi = Wcb[col];
#pragma unroll
    for (int i = 0; i < 4; ++i) {
      Tw[(quad * 4 + i) * 264 + col]      = f2bf((c0[i] + bi) * 0.0625f);
      Tw[(16 + quad * 4 + i) * 264 + col] = f2bf((c1[i] + bi) * 0.0625f);
    }
  }
#pragma unroll
  for (int it = 0; it < 16; ++it) {
    const int gsub = it * 64 + lane;
    const int row = gsub >> 5, c16 = gsub & 31;
    *(u16x8*)&Qb[(size_t)(mbase + row) * 256 + c16 * 8] =
        *(const u16x8*)&Tw[row * 264 + c16 * 8];
  }
  // K
#pragma unroll 4
  for (int nt = 0; nt < 16; ++nt) {
    s16x8 bf = *(const s16x8*)&WqT[(size_t)(256 + nt * 16 + lo) * 32 + quad * 8];
    f32x4 c0 = {0.f, 0.f, 0.f, 0.f}, c1 = {0.f, 0.f, 0.f, 0.f};
    c0 = __builtin_amdgcn_mfma_f32_16x16x32_bf16(af0, bf, c0, 0, 0, 0);
    c1 = __builtin_amdgcn_mfma_f32_16x16x32_bf16(af1, bf, c1, 0, 0, 0);
    const int col = nt * 16 + lo;
    const float bi = Wcb[256 + col];
#pragma unroll
    for (int i = 0; i < 4; ++i) {
      Tw[(quad * 4 + i) * 264 + col]      = f2bf(c0[i] + bi);
      Tw[(16 + quad * 4 + i) * 264 + col] = f2bf(c1[i] + bi);
    }
  }
#pragma unroll
  for (int it = 0; it < 16; ++it) {
    const int gsub = it * 64 + lane;
    const int row = gsub >> 5, c16 = gsub & 31;
    *(u16x8*)&Kb[(size_t)(mbase + row) * 256 + c16 * 8] =
        *(const u16x8*)&Tw[row * 264 + c16 * 8];
  }
  // V transposed, kt-tiled: Vtt[(b*32+ktq)*8192 + d*32 + t_local]
#pragma unroll 4
  for (int nt2 = 0; nt2 < 16; ++nt2) {
    s16x8 aw = *(const s16x8*)&WqT[(size_t)(512 + nt2 * 16 + lo) * 32 + quad * 8];
    f32x4 c0 = {0.f, 0.f, 0.f, 0.f}, c1 = {0.f, 0.f, 0.f, 0.f};
    c0 = __builtin_amdgcn_mfma_f32_16x16x32_bf16(aw, af0, c0, 0, 0, 0);
    c1 = __builtin_amdgcn_mfma_f32_16x16x32_bf16(aw, af1, c1, 0, 0, 0);
#pragma unroll
    for (int i = 0; i < 4; ++i) {
      const int d = nt2 * 16 + quad * 4 + i;
      const float bv = Wcb[512 + d];
      Tw[d * 32 + lo]      = f2bf(c0[i] + bv);
      Tw[d * 32 + 16 + lo] = f2bf(c1[i] + bv);
    }
  }
  {
    const int ktq = (mbase >> 5) & 31;
    const size_t vb = ((size_t)b * 32 + ktq) * 8192;
#pragma unroll
    for (int it = 0; it < 16; ++it) {
      const int gsub = it * 64 + lane;
      *(u16x8*)&Vtt[vb + gsub * 8] = *(const u16x8*)&Tw[gsub * 8];
    }
  }
}

// ---------------- flash attention, double-buffered LDS staging; self-finalizing loss ----
// 512 blocks, heavy-first, XCD-pinned by b. One barrier per kt-step; loads for kt+1
// issue right after the barrier and land during compute on kt (drain overlapped).
// SMEM (shorts): buf0 K[0,8192) V[8192,16384) | buf1 K[16384,24576) V[24576,32768)
//                P [32768,35328) ; epilogue OL overlays buf0; loss red at [35000+].
__global__ __launch_bounds__(256) void attn_kernel(const unsigned short* __restrict__ Qb,
                                                   const unsigned short* __restrict__ Kb,
                                                   const unsigned short* __restrict__ Vtt,
                                                   const unsigned short* __restrict__ WfT,
                                                   const float* __restrict__ bfp,
                                                   const float* __restrict__ x,
                                                   const float* __restrict__ sgpart,
                                                   float* __restrict__ lsum,
                                                   unsigned int* __restrict__ total,
                                                   float* __restrict__ out) {
  __shared__ unsigned short SMEM[35328];  // 70656 B -> 2 blocks/CU
  const int g = blockIdx.x;
  const int j = g >> 3;
  const int b = (g & 7) * 4 + (j & 3);  // XCD id (g%8) pinned per b
  const int qt = 15 - (j >> 2);         // heavy-first
  const int tid = threadIdx.x;
  const int w = tid >> 6, lane = tid & 63;
  const int lo = lane & 15, quad = lane >> 4;

  const int qr0 = qt * 64 + w * 16;
  const size_t kbase = (size_t)b << 10;

  s16x8 qf[8];
  const size_t qrow = (kbase + qr0 + lo) * 256;
#pragma unroll
  for (int kc = 0; kc < 8; ++kc) qf[kc] = *(const s16x8*)&Qb[qrow + kc * 32 + quad * 8];

  f32x4 O[16];
#pragma unroll
  for (int nt = 0; nt < 16; ++nt) O[nt] = (f32x4){0.f, 0.f, 0.f, 0.f};
  f32x4 Ol = {0.f, 0.f, 0.f, 0.f};
  s16x8 ones;
#pragma unroll
  for (int jj = 0; jj < 8; ++jj) ones[jj] = (short)0x3F80;

  // hoisted staging addresses (swizzle terms kt-invariant, verified R8-R10)
  const int c16p = tid & 31;
  const int keyr = tid >> 5;
  const int c16s = (c16p & 24) | ((c16p & 7) ^ keyr);
  const unsigned short* kgp = Kb + (kbase << 8) + keyr * 256 + c16s * 8;
  const int dql = tid >> 2;
  const int cpq = (tid & 3) ^ ((tid >> 3) & 3);
  const unsigned short* vgp = Vtt + (size_t)b * 262144 + dql * 32 + cpq * 8;
  const int ldst = (w * 64) * 8;  // wave-uniform lane-block offset within a 4KB slab

  unsigned short* myp = &SMEM[32768 + w * 640];
  const int lo7 = lo & 7;
  const int nk = 2 * (qt + 1);

  // prologue: stage tile 0 into buf 0
#pragma unroll
  for (int it = 0; it < 4; ++it) g2l16(kgp + it * 2048, &SMEM[it * 2048 + ldst]);
#pragma unroll
  for (int it = 0; it < 4; ++it) g2l16(vgp + it * 2048, &SMEM[8192 + it * 2048 + ldst]);
  kgp += 8192; vgp += 8192;

  for (int kt = 0; kt < nk; ++kt) {
    const int k0 = kt * 32;
    __syncthreads();  // drains own vmcnt -> buf[kt&1] fully staged & visible
    const int cur = (kt & 1) << 14;
    if (kt + 1 < nk) {  // issue next tile into the other buffer; lands during compute
      const int nxt = ((kt + 1) & 1) << 14;
#pragma unroll
      for (int it = 0; it < 4; ++it) g2l16(kgp + it * 2048, &SMEM[nxt + it * 2048 + ldst]);
#pragma unroll
      for (int it = 0; it < 4; ++it)
        g2l16(vgp + it * 2048, &SMEM[nxt + 8192 + it * 2048 + ldst]);
      kgp += 8192; vgp += 8192;
    }

    if (k0 <= qr0 + 15) {
      f32x4 s0 = {0.f, 0.f, 0.f, 0.f}, s1 = {0.f, 0.f, 0.f, 0.f};
#pragma unroll
      for (int kc = 0; kc < 8; ++kc) {
        const int c16 = kc * 4 + quad;
        const int cs = (c16 & 24) | ((c16 & 7) ^ lo7);
        s16x8 kf0 = *(const s16x8*)&SMEM[cur + (lo * 32 + cs) * 8];
        s16x8 kf1 = *(const s16x8*)&SMEM[cur + ((16 + lo) * 32 + cs) * 8];
        s0 = __builtin_amdgcn_mfma_f32_16x16x32_bf16(qf[kc], kf0, s0, 0, 0, 0);
        s1 = __builtin_amdgcn_mfma_f32_16x16x32_bf16(qf[kc], kf1, s1, 0, 0, 0);
      }
      if (k0 + 31 > qr0) {  // straddling tile: causal mask
#pragma unroll
        for (int ii = 0; ii < 4; ++ii) {
          const int row = qr0 + quad * 4 + ii;
          if (k0 + lo > row) s0[ii] = -1e30f;
          if (k0 + 16 + lo > row) s1[ii] = -1e30f;
        }
      }
#pragma unroll
      for (int ii = 0; ii < 4; ++ii) {
        myp[(quad * 4 + ii) * 40 + lo]      = f2bf(__expf(s0[ii] - SM_M));
        myp[(quad * 4 + ii) * 40 + 16 + lo] = f2bf(__expf(s1[ii] - SM_M));
      }
      s16x8 pf = *(const s16x8*)&myp[lo * 40 + quad * 8];
      Ol = __builtin_amdgcn_mfma_f32_16x16x32_bf16(pf, ones, Ol, 0, 0, 0);
#pragma unroll
      for (int nt = 0; nt < 16; ++nt) {
        const int d = nt * 16 + lo;
        const int cp = quad ^ ((d >> 1) & 3);
        s16x8 vf = *(const s16x8*)&SMEM[cur + 8192 + ((d << 2) + cp) * 8];
        O[nt] = __builtin_amdgcn_mfma_f32_16x16x32_bf16(pf, vf, O[nt], 0, 0, 0);
      }
    }
  }
  __syncthreads();  // all waves done with buffers before OL overlay

  // ---- epilogue: normalize O -> LDS A-layout -> head GEMM -> fused MSE ----
  float inv4[4];
#pragma unroll
  for (int ii = 0; ii < 4; ++ii) inv4[ii] = 1.f / Ol[ii];
  unsigned short* OLw = &SMEM[w * 4224];
#pragma unroll
  for (int nt = 0; nt < 16; ++nt)
#pragma unroll
    for (int ii = 0; ii < 4; ++ii)
      OLw[(quad * 4 + ii) * 264 + nt * 16 + lo] = f2bf(O[nt][ii] * inv4[ii]);

  s16x8 af[8];
#pragma unroll
  for (int kc = 0; kc < 8; ++kc)
    af[kc] = *(const s16x8*)&OLw[lo * 264 + kc * 32 + quad * 8];

  float S = 0.f, SS = 0.f;
#pragma unroll
  for (int i = 0; i < 8; ++i) {
    S += sgpart[(b * 8 + i) * 2];
    SS += sgpart[(b * 8 + i) * 2 + 1];
  }
  const float mean = S * (1.f / (float)L_SZ);
  const float var = (SS - S * mean) * (1.f / (float)(L_SZ - 1));
  const float invb = 1.f / (sqrtf(var) + 1e-5f);

  float lacc = 0.f;
#pragma unroll
  for (int nt = 0; nt < 2; ++nt) {
    f32x4 acc = {0.f, 0.f, 0.f, 0.f};
#pragma unroll
    for (int kc = 0; kc < 8; ++kc) {
      s16x8 bfr = *(const s16x8*)&WfT[(size_t)(nt * 16 + lo) * 256 + kc * 32 + quad * 8];
      acc = __builtin_amdgcn_mfma_f32_16x16x32_bf16(af[kc], bfr, acc, 0, 0, 0);
    }
    const float ba = bfp[nt * 16 + lo];
    const int p = nt * 16 + lo;
#pragma unroll
    for (int ii = 0; ii < 4; ++ii) {
      const int t = qr0 + quad * 4 + ii;
      if (t < 1023) {
        const float pr = acc[ii] + ba;
        const float tg = (x[(size_t)b * L_SZ + (t + 1) * 32 + p] - mean) * invb;
        const float d = pr - tg;
        lacc += d * d;
      }
    }
  }
#pragma unroll
  for (int off = 32; off >= 1; off >>= 1) lacc += __shfl_down(lacc, off);
  float* redf = (float*)&SMEM[35000];
  unsigned int* flag = (unsigned int*)&SMEM[35100];
  if (lane == 0) redf[w] = lacc;
  __syncthreads();

  // ---- in-kernel loss finalize (counter pattern verified numerically in R10) ----
  if (tid == 0) {
    atomicAdd(lsum, redf[0] + redf[1] + redf[2] + redf[3]);
    __threadfence();
    unsigned int prev = atomicAdd(total, 1u);
    flag[0] = (prev == 511u) ? 1u : 0u;
  }
  __syncthreads();
  if (flag[0] && tid == 0) {
    float tot = atomicAdd(lsum, 0.0f);  // device-scope read including all adds
    out[0] = tot * (1.f / (float)(B_SZ * (T_SZ - 1) * PS_SZ));
  }
}

extern "C" void kernel_launch(void* const* d_in, const int* in_sizes, int n_in,
                              void* d_out, int out_size, void* d_ws, size_t ws_size,
                              hipStream_t stream) {
  const float* x      = (const float*)d_in[0];
  const float* W_proj = (const float*)d_in[1];
  const float* b_proj = (const float*)d_in[2];
  const float* W_qkv  = (const float*)d_in[3];
  const float* b_qkv  = (const float*)d_in[4];
  const float* W_out  = (const float*)d_in[5];
  const float* b_out  = (const float*)d_in[6];
  const float* W_head = (const float*)d_in[7];
  const float* b_head = (const float*)d_in[8];
  float* out = (float*)d_out;
  char* ws = (char*)d_ws;

  unsigned short* Qb     = (unsigned short*)ws;
  unsigned short* Kb     = (unsigned short*)(ws + (16ull << 20));
  unsigned short* Vtt    = (unsigned short*)(ws + (32ull << 20));
  char* tail = ws + (48ull << 20);
  float*          Wcb    = (float*)tail;                        // 768 fp32 folded qkv bias
  unsigned short* WqT    = (unsigned short*)(tail + 4096);      // 768x32 bf16
  unsigned short* WfT    = (unsigned short*)(tail + 65536);     // 32x256 bf16
  float*          bfp    = (float*)(tail + 98304);              // 32 fp32
  float*          sgpart = (float*)(tail + 102400);             // 256x2 fp32
  unsigned int*   total  = (unsigned int*)(tail + 106496);      // 1 ctr
  float*          lsum   = (float*)(tail + 106496 + 64);        // 1 fp32

  prep_kernel<<<389, 256, 0, stream>>>(x, sgpart, W_proj, b_proj, W_qkv, b_qkv,
                                       W_out, b_out, W_head, b_head,
                                       Wcb, WqT, WfT, bfp, total, lsum);
  qkv_kernel<<<256, 256, 0, stream>>>(x, sgpart, WqT, Wcb, Qb, Kb, Vtt);
  attn_kernel<<<512, 256, 0, stream>>>(Qb, Kb, Vtt, WfT, bfp, x, sgpart, lsum, total, out);
}